// Round 1
// 1813.570 us; speedup vs baseline: 1.9084x; 1.9084x over previous
//
#include <hip/hip_runtime.h>

#define TPB 256
constexpr int LS = 264600;          // 6.0 s * 44100 Hz
constexpr int N1 = 525;             // LS = N1 * N2
constexpr int N2 = 504;
constexpr int ROWS = 32;            // S*C = 16*2
constexpr int M_FFT = 16384;        // Bluestein conv length >= 2*NL-1 (NL<=8192)
constexpr float TWO_PI_F = 6.28318530717958647692f;
constexpr float PI_F     = 3.14159265358979323846f;

__device__ __forceinline__ int rev7(int x) { return (int)(__brev((unsigned)x) >> 25); }
__device__ __forceinline__ float2 cmul(float2 a, float2 b) {
    return make_float2(a.x * b.x - a.y * b.y, a.x * b.y + a.y * b.x);
}

// ---------------------------------------------------------------------------
// K0: per-bin scan of G for nonzero head/tail block sizes (exact-0 padding).
// ---------------------------------------------------------------------------
__global__ void k0_scan(const float* __restrict__ G, int NL, int* __restrict__ hnh) {
    const int j = blockIdx.x;
    __shared__ int s_first, s_last;
    if (threadIdx.x == 0) { s_first = NL; s_last = -1; }
    __syncthreads();
    const float* Gj = G + (size_t)j * NL;
    for (int m = threadIdx.x; m < NL; m += blockDim.x) {
        if (Gj[m] == 0.0f) {
            atomicMin(&s_first, m);
            atomicMax(&s_last, m);
        }
    }
    __syncthreads();
    if (threadIdx.x == 0) {
        int h  = s_first;
        int nh = (s_last >= 0) ? (NL - 1 - s_last) : 0;
        hnh[2 * j]     = h;
        hnh[2 * j + 1] = nh;
    }
}

// ---------------------------------------------------------------------------
// K1: 525-point DFT per (n2, r), split 525 = 25 x 21 (Cooley-Tukey in LDS).
//   t = 21a + b (a<25, b<21), k = alpha + 25*beta (alpha<25, beta<21)
//   X[alpha+25b'] = sum_b W21^{b*beta} * ( W525^{b*alpha} *
//                         sum_a x[21a+b] * W25^{a*alpha} )
// Work: 525*(25+21) MACs vs 525^2 direct (11.4x less). Small twiddle tables
// (w25/w21: <=2-way bank aliasing = free) replace the conflicted 525-table.
// ---------------------------------------------------------------------------
__global__ __launch_bounds__(TPB) void k1_dft525(const float* __restrict__ x,
                                                 float2* __restrict__ A) {
    const int n2 = blockIdx.x;
    const int r  = blockIdx.y;
    __shared__ float  xs[N1];
    __shared__ float2 ys[N1];
    __shared__ float2 w25[25];
    __shared__ float2 w21[21];
    const float* xr = x + (size_t)r * LS + n2;
    for (int t = threadIdx.x; t < N1; t += TPB) {
        xs[t] = xr[(size_t)t * N2];
    }
    if (threadIdx.x < 25) {
        float a = -TWO_PI_F * (float)threadIdx.x / 25.0f;
        float s, c; sincosf(a, &s, &c);
        w25[threadIdx.x] = make_float2(c, s);
    } else if (threadIdx.x >= 32 && threadIdx.x < 53) {
        int k = threadIdx.x - 32;
        float a = -TWO_PI_F * (float)k / 21.0f;
        float s, c; sincosf(a, &s, &c);
        w21[k] = make_float2(c, s);
    }
    __syncthreads();
    // step 1 (+ fused inter-stage twiddle): real input -> 2 FMA per tap
    for (int i = threadIdx.x; i < N1; i += TPB) {
        int alpha = i % 25, b = i / 25;
        float re = 0.f, im = 0.f;
        int iw = 0, it = b;
        #pragma unroll
        for (int a = 0; a < 25; ++a) {
            float  v = xs[it];
            float2 w = w25[iw];
            re = fmaf(v, w.x, re);
            im = fmaf(v, w.y, im);
            it += 21;
            iw += alpha; if (iw >= 25) iw -= 25;
        }
        float ang = -TWO_PI_F * (float)(b * alpha) / (float)N1;
        float s, c; sincosf(ang, &s, &c);
        ys[i] = make_float2(re * c - im * s, re * s + im * c);   // ys[alpha+25b]
    }
    __syncthreads();
    // step 3 + final four-step twiddle W_LS^{k1*n2}
    for (int k = threadIdx.x; k < N1; k += TPB) {
        int alpha = k % 25, beta = k / 25;
        float re = 0.f, im = 0.f;
        int iw = 0, iy = alpha;
        #pragma unroll
        for (int b = 0; b < 21; ++b) {
            float2 v = ys[iy];
            float2 w = w21[iw];
            re = fmaf(v.x, w.x, re); re = fmaf(-v.y, w.y, re);
            im = fmaf(v.x, w.y, im); im = fmaf( v.y, w.x, im);
            iy += 25;
            iw += beta; if (iw >= 21) iw -= 21;
        }
        float ang = -TWO_PI_F * (float)(k * n2) / (float)LS;
        float s, c; sincosf(ang, &s, &c);
        A[((size_t)r * N1 + k) * N2 + n2] = make_float2(re * c - im * s, re * s + im * c);
    }
}

// ---------------------------------------------------------------------------
// K2: 504-point DFT per (k1, r), split 504 = 21 x 24 (Cooley-Tukey in LDS).
//   t = 24a + b (a<21, b<24), k = alpha + 21*beta (alpha<21, beta<24)
// Work: 504*(21+24) MACs vs 504^2 direct (11x less).
// ---------------------------------------------------------------------------
__global__ __launch_bounds__(TPB) void k2_dft504(float2* __restrict__ A) {
    const int k1 = blockIdx.x;
    const int r  = blockIdx.y;
    __shared__ float2 as[N2];
    __shared__ float2 ys[N2];
    __shared__ float2 w21[21];
    __shared__ float2 w24[24];
    float2* row = A + ((size_t)r * N1 + k1) * N2;
    for (int t = threadIdx.x; t < N2; t += TPB) as[t] = row[t];
    if (threadIdx.x < 21) {
        float a = -TWO_PI_F * (float)threadIdx.x / 21.0f;
        float s, c; sincosf(a, &s, &c);
        w21[threadIdx.x] = make_float2(c, s);
    } else if (threadIdx.x >= 32 && threadIdx.x < 56) {
        int k = threadIdx.x - 32;
        float a = -TWO_PI_F * (float)k / 24.0f;
        float s, c; sincosf(a, &s, &c);
        w24[k] = make_float2(c, s);
    }
    __syncthreads();
    // step 1 (+ fused inter-stage twiddle)
    for (int i = threadIdx.x; i < N2; i += TPB) {
        int alpha = i % 21, b = i / 21;
        float re = 0.f, im = 0.f;
        int iw = 0, it = b;
        #pragma unroll
        for (int a = 0; a < 21; ++a) {
            float2 v = as[it];
            float2 w = w21[iw];
            re = fmaf(v.x, w.x, re); re = fmaf(-v.y, w.y, re);
            im = fmaf(v.x, w.y, im); im = fmaf( v.y, w.x, im);
            it += 24;
            iw += alpha; if (iw >= 21) iw -= 21;
        }
        float ang = -TWO_PI_F * (float)(b * alpha) / (float)N2;
        float s, c; sincosf(ang, &s, &c);
        ys[i] = make_float2(re * c - im * s, re * s + im * c);   // ys[alpha+21b]
    }
    __syncthreads();
    // step 3: in-place write back (row fully consumed into as before this)
    for (int k = threadIdx.x; k < N2; k += TPB) {
        int alpha = k % 21, beta = k / 21;
        float re = 0.f, im = 0.f;
        int iw = 0, iy = alpha;
        #pragma unroll
        for (int b = 0; b < 24; ++b) {
            float2 v = ys[iy];
            float2 w = w24[iw];
            re = fmaf(v.x, w.x, re); re = fmaf(-v.y, w.y, re);
            im = fmaf(v.x, w.y, im); im = fmaf( v.y, w.x, im);
            iy += 21;
            iw += beta; if (iw >= 24) iw -= 24;
        }
        row[k] = make_float2(re, im);
    }
}

// ---------------------------------------------------------------------------
// K_SETUP: chirp tables. bchirp[n] = e^{+i pi n^2/NL}, kc[i] = e^{-i pi d^2/NL}
// wrapped to M (linear-conv kernel), exact int64 phase reduction mod 2*NL.
// ---------------------------------------------------------------------------
__global__ void k_setup(float2* __restrict__ kc, float2* __restrict__ bchirp, int NL) {
    int t = blockIdx.x * blockDim.x + threadIdx.x;
    long long twoNL = 2LL * NL;
    if (t < M_FFT) {
        long long d = 0; bool act = false;
        if (t < NL)              { d = t;        act = true; }
        else if (t > M_FFT - NL) { d = t - M_FFT; act = true; }
        float2 v = make_float2(0.f, 0.f);
        if (act) {
            long long ph = (d * d) % twoNL;
            float th = -PI_F * (float)ph / (float)NL;
            float s, c; sincosf(th, &s, &c);
            v = make_float2(c, s);
        }
        kc[t] = v;
    } else {
        int n = t - M_FFT;
        if (n < NL) {
            long long ph = ((long long)n * n) % twoNL;
            float th = PI_F * (float)ph / (float)NL;
            float s, c; sincosf(th, &s, &c);
            bchirp[n] = make_float2(c, s);
        }
    }
}

// ---------------------------------------------------------------------------
// In-LDS radix-2 FFT-128 helpers. 16 FFTs per 256-thread block, 16 thr/FFT.
// DIF: natural in -> bitrev out, W = e^{-2pi i k/128}.
// DIT: bitrev in -> natural out, conj twiddles (unnormalized inverse).
// ---------------------------------------------------------------------------
__device__ void fft128_dif(float2 (*ld)[129], const float2* tw, int f, int q) {
    for (int ls = 6; ls >= 0; --ls) {
        int span = 1 << ls;
        for (int b = q; b < 64; b += 16) {
            int j = b & (span - 1);
            int g = b >> ls;
            int u = (g << (ls + 1)) + j;
            int v = u + span;
            float2 A = ld[f][u], B = ld[f][v];
            float2 s = make_float2(A.x + B.x, A.y + B.y);
            float2 d = make_float2(A.x - B.x, A.y - B.y);
            ld[f][u] = s;
            ld[f][v] = cmul(d, tw[j << (6 - ls)]);
        }
        __syncthreads();
    }
}

__device__ void fft128_dit(float2 (*ld)[129], const float2* tw, int f, int q) {
    for (int ls = 0; ls <= 6; ++ls) {
        int span = 1 << ls;
        for (int b = q; b < 64; b += 16) {
            int j = b & (span - 1);
            int g = b >> ls;
            int u = (g << (ls + 1)) + j;
            int v = u + span;
            float2 w = tw[j << (6 - ls)];
            w.y = -w.y;                       // conj -> e^{+...}
            float2 A = ld[f][u];
            float2 t = cmul(ld[f][v], w);
            ld[f][u] = make_float2(A.x + t.x, A.y + t.y);
            ld[f][v] = make_float2(A.x - t.x, A.y - t.y);
        }
        __syncthreads();
    }
}

#define FFT_PROLOG                                                        \
    __shared__ float2 ld[16][129];                                        \
    __shared__ float2 tw[64];                                             \
    if (threadIdx.x < 64) {                                               \
        float th = -TWO_PI_F * (float)threadIdx.x / 128.0f;               \
        float s, c; sincosf(th, &s, &c);                                  \
        tw[threadIdx.x] = make_float2(c, s);                              \
    }

// Forward step 1: column FFTs (over r, stride 128) + twiddle W_M^{-c*k1}.
__global__ __launch_bounds__(TPB) void kfft_cols_fwd(float2* __restrict__ P) {
    const int cg = blockIdx.x;                    // [0,8)
    const size_t vb = (size_t)blockIdx.y * M_FFT;
    FFT_PROLOG
    const int c0 = cg * 16;
    for (int i = threadIdx.x; i < 2048; i += TPB) {
        int cl = i & 15, r = i >> 4;
        ld[cl][r] = P[vb + (c0 + cl) + 128 * r];
    }
    __syncthreads();
    fft128_dif(ld, tw, threadIdx.x >> 4, threadIdx.x & 15);
    for (int i = threadIdx.x; i < 2048; i += TPB) {
        int cl = i & 15, pos = i >> 4;
        int c = c0 + cl;
        int k1 = rev7(pos);
        float th = -TWO_PI_F * (float)(c * k1) / (float)M_FFT;
        float s, co; sincosf(th, &s, &co);
        P[vb + c + 128 * pos] = cmul(ld[cl][pos], make_float2(co, s));
    }
}

// Forward step 2: row FFTs (contiguous), no twiddle.
__global__ __launch_bounds__(TPB) void kfft_rows_fwd(float2* __restrict__ P) {
    const int rg = blockIdx.x;
    const size_t vb = (size_t)blockIdx.y * M_FFT;
    FFT_PROLOG
    const int R0 = rg * 16;
    for (int i = threadIdx.x; i < 2048; i += TPB) {
        int fl = i >> 7, c = i & 127;
        ld[fl][c] = P[vb + (size_t)(R0 + fl) * 128 + c];
    }
    __syncthreads();
    fft128_dif(ld, tw, threadIdx.x >> 4, threadIdx.x & 15);
    for (int i = threadIdx.x; i < 2048; i += TPB) {
        int fl = i >> 7, pos = i & 127;
        P[vb + (size_t)(R0 + fl) * 128 + pos] = ld[fl][pos];
    }
}

// Inverse step 1: row DIT FFTs; multiply KF at load; twiddle W_M^{+rev7(R)*pos}
// after. (Input rows are sigma(k1), elements at sigma(k2) -> DIT bitrev-in.)
__global__ __launch_bounds__(TPB) void kfft_rows_inv(float2* __restrict__ P,
                                                     const float2* __restrict__ KF) {
    const int rg = blockIdx.x;
    const size_t vb = (size_t)blockIdx.y * M_FFT;
    FFT_PROLOG
    const int R0 = rg * 16;
    for (int i = threadIdx.x; i < 2048; i += TPB) {
        int fl = i >> 7, c = i & 127;
        size_t p = (size_t)(R0 + fl) * 128 + c;
        ld[fl][c] = cmul(P[vb + p], KF[p]);
    }
    __syncthreads();
    fft128_dit(ld, tw, threadIdx.x >> 4, threadIdx.x & 15);
    for (int i = threadIdx.x; i < 2048; i += TPB) {
        int fl = i >> 7, pos = i & 127;
        int R = R0 + fl;
        int k1 = rev7(R);
        float th = TWO_PI_F * (float)(k1 * pos) / (float)M_FFT;
        float s, co; sincosf(th, &s, &co);
        P[vb + (size_t)R * 128 + pos] = cmul(ld[fl][pos], make_float2(co, s));
    }
}

// Inverse step 2: column DIT FFTs (rows are sigma(k1) -> bitrev-in), output
// natural: y[n1+128*n2] lands at p = n1+128*n2. No twiddle.
__global__ __launch_bounds__(TPB) void kfft_cols_inv(float2* __restrict__ P) {
    const int cg = blockIdx.x;
    const size_t vb = (size_t)blockIdx.y * M_FFT;
    FFT_PROLOG
    const int c0 = cg * 16;
    for (int i = threadIdx.x; i < 2048; i += TPB) {
        int cl = i & 15, r = i >> 4;
        ld[cl][r] = P[vb + (c0 + cl) + 128 * r];
    }
    __syncthreads();
    fft128_dit(ld, tw, threadIdx.x >> 4, threadIdx.x & 15);
    for (int i = threadIdx.x; i < 2048; i += TPB) {
        int cl = i & 15, pos = i >> 4;
        P[vb + (c0 + cl) + 128 * pos] = ld[cl][pos];
    }
}

// ---------------------------------------------------------------------------
// K_GATHER: build a[m] = c[m]*bchirp[m] zero-padded to M for each transform.
// c[m] = G[j,m] * ft[r, idx[j,m]], nonzero only in head [0,h) / tail blocks.
// ---------------------------------------------------------------------------
__global__ __launch_bounds__(TPB) void k_gather(const float* __restrict__ Gm,
        const int* __restrict__ idxp, const float2* __restrict__ A,
        const int* __restrict__ hnh, const float2* __restrict__ bchirp,
        float2* __restrict__ P, int NB, int NL, int vbase) {
    const int vg = vbase + blockIdx.x;
    const int r = vg / NB, j = vg % NB;
    const int h = hnh[2 * j], nh = hnh[2 * j + 1];
    const float* Gj = Gm + (size_t)j * NL;
    const int*   ij = idxp + (size_t)j * NL;
    const float2* Ar = A + (size_t)r * LS;
    float2* Pv = P + (size_t)blockIdx.x * M_FFT;
    const int tail0 = NL - nh;
    for (int i = threadIdx.x; i < M_FFT; i += TPB) {
        float2 val = make_float2(0.f, 0.f);
        if (i < h || (i >= tail0 && i < NL)) {
            int k = ij[i];
            int k1 = k % N1, k2 = k / N1;
            float2 f = Ar[(size_t)k1 * N2 + k2];
            float  g = Gj[i];
            val = cmul(make_float2(f.x * g, f.y * g), bchirp[i]);
        }
        Pv[i] = val;
    }
}

// ---------------------------------------------------------------------------
// K_FIN: out[n] = P[n] * bchirp[n] * 100/(NL*M)  (natural order, coalesced).
// ---------------------------------------------------------------------------
__global__ __launch_bounds__(TPB) void k_fin(const float2* __restrict__ P,
        const float2* __restrict__ bchirp, float2* __restrict__ out,
        int NL, int vbase) {
    const int vloc = blockIdx.y;
    const float2* Pv = P + (size_t)vloc * M_FFT;
    float2* outv = out + (size_t)(vbase + vloc) * NL;
    const float sc = 100.0f / ((float)NL * (float)M_FFT);
    for (int n = blockIdx.x * TPB + threadIdx.x; n < NL; n += gridDim.x * TPB) {
        float2 y = cmul(Pv[n], bchirp[n]);
        outv[n] = make_float2(y.x * sc, y.y * sc);
    }
}

// ---------------------------------------------------------------------------
// Legacy direct zoom-IDFT (round-1 proven) — fallback if ws too small.
// ---------------------------------------------------------------------------
__global__ __launch_bounds__(TPB) void k3_idft(const float* __restrict__ G,
                                               const int*  __restrict__ idxp,
                                               const float2* __restrict__ FT,
                                               const int*  __restrict__ hnh,
                                               float2* __restrict__ out,
                                               int NB, int NL) {
    extern __shared__ float2 cls[];
    const int j = blockIdx.x;
    const int r = blockIdx.y;
    const int h  = hnh[2 * j];
    const int nh = hnh[2 * j + 1];
    const int Lg = h + nh;
    const float* Gj = G    + (size_t)j * NL;
    const int*   ij = idxp + (size_t)j * NL;

    for (int t = threadIdx.x; t < Lg; t += TPB) {
        int m = (t < h) ? t : (NL - nh + (t - h));
        int k = ij[m];
        float2 f = FT[((size_t)r * N1 + (k % N1)) * N2 + (k / N1)];
        float  g = Gj[m];
        cls[t] = make_float2(f.x * g, f.y * g);
    }
    __syncthreads();

    const float scale = 100.0f / (float)NL;
    const float w0 = TWO_PI_F / (float)NL;
    float2* outr = out + ((size_t)r * NB + j) * NL;

    for (int n_base = 0; n_base < NL; n_base += 4 * TPB) {
        int   n[4];
        float are[4], aim[4], twr[4], twi[4], str[4], sti[4];
        #pragma unroll
        for (int u = 0; u < 4; ++u) {
            n[u] = n_base + u * TPB + (int)threadIdx.x;
            are[u] = 0.f; aim[u] = 0.f;
            float s, c; sincosf(w0 * (float)(n[u] % NL), &s, &c);
            str[u] = c; sti[u] = s;
            twr[u] = 1.f; twi[u] = 0.f;
        }
        for (int t = 0; t < h; ++t) {
            if ((t & 255) == 0) {
                #pragma unroll
                for (int u = 0; u < 4; ++u) {
                    int mm = (int)(((long long)t * (long long)n[u]) % NL);
                    float s, c; sincosf(w0 * (float)mm, &s, &c);
                    twr[u] = c; twi[u] = s;
                }
            }
            float2 cv = cls[t];
            #pragma unroll
            for (int u = 0; u < 4; ++u) {
                are[u] = fmaf(cv.x, twr[u], are[u]);
                are[u] = fmaf(-cv.y, twi[u], are[u]);
                aim[u] = fmaf(cv.x, twi[u], aim[u]);
                aim[u] = fmaf(cv.y, twr[u], aim[u]);
                float nr = twr[u] * str[u] - twi[u] * sti[u];
                float ni = twr[u] * sti[u] + twi[u] * str[u];
                twr[u] = nr; twi[u] = ni;
            }
        }
        const int m0 = NL - nh;
        for (int t = 0; t < nh; ++t) {
            if ((t & 255) == 0) {
                #pragma unroll
                for (int u = 0; u < 4; ++u) {
                    int mm = (int)(((long long)(m0 + t) * (long long)n[u]) % NL);
                    float s, c; sincosf(w0 * (float)mm, &s, &c);
                    twr[u] = c; twi[u] = s;
                }
            }
            float2 cv = cls[h + t];
            #pragma unroll
            for (int u = 0; u < 4; ++u) {
                are[u] = fmaf(cv.x, twr[u], are[u]);
                are[u] = fmaf(-cv.y, twi[u], are[u]);
                aim[u] = fmaf(cv.x, twi[u], aim[u]);
                aim[u] = fmaf(cv.y, twr[u], aim[u]);
                float nr = twr[u] * str[u] - twi[u] * sti[u];
                float ni = twr[u] * sti[u] + twi[u] * str[u];
                twr[u] = nr; twi[u] = ni;
            }
        }
        #pragma unroll
        for (int u = 0; u < 4; ++u) {
            if (n[u] < NL) outr[n[u]] = make_float2(are[u] * scale, aim[u] * scale);
        }
    }
}

// ---------------------------------------------------------------------------
static inline size_t align256(size_t x) { return (x + 255) & ~(size_t)255; }

extern "C" void kernel_launch(void* const* d_in, const int* in_sizes, int n_in,
                              void* d_out, int out_size, void* d_ws, size_t ws_size,
                              hipStream_t stream) {
    const float* x   = (const float*)d_in[0];
    const float* Gm  = (const float*)d_in[1];
    const int*   idx = (const int*)d_in[2];
    float2*      out = (float2*)d_out;

    const int p  = in_sizes[1];
    const int NB = (p % 114 == 0) ? 114 : 115;
    const int NL = p / NB;
    const int B  = NB * ROWS;

    // ws layout
    size_t hnh_off    = 0;
    size_t bchirp_off = align256(hnh_off + 2048);
    size_t kc_off     = align256(bchirp_off + (size_t)NL * 8);
    size_t A_off      = align256(kc_off + (size_t)M_FFT * 8);
    size_t P_off      = align256(A_off + (size_t)ROWS * LS * 8);

    int*    hnh    = (int*)((char*)d_ws + hnh_off);
    float2* bchirp = (float2*)((char*)d_ws + bchirp_off);
    float2* kc     = (float2*)((char*)d_ws + kc_off);
    float2* A      = (float2*)((char*)d_ws + A_off);
    float2* P      = (float2*)((char*)d_ws + P_off);

    // pick chunk count (fewest chunks whose P fits); 0 => legacy fallback
    int nc = 0, nTc = 0;
    if (2 * NL - 1 <= M_FFT) {
        const int cand[] = {1, 2, 3, 4, 6, 8, 12, 16, 24, 32, 48, 64};
        for (int t : cand) {
            int ch = (B + t - 1) / t;
            if (P_off + (size_t)ch * M_FFT * 8 <= ws_size) { nc = t; nTc = ch; break; }
        }
    }

    k0_scan<<<dim3(NB), TPB, 0, stream>>>(Gm, NL, hnh);
    k1_dft525<<<dim3(N2, ROWS), TPB, 0, stream>>>(x, A);
    k2_dft504<<<dim3(N1, ROWS), TPB, 0, stream>>>(A);

    if (nc > 0) {
        int setup_blocks = (M_FFT + NL + TPB - 1) / TPB;
        k_setup<<<dim3(setup_blocks), TPB, 0, stream>>>(kc, bchirp, NL);
        // KF = fwd-FFT(kc) in the pipeline's stored layout
        kfft_cols_fwd<<<dim3(8, 1), TPB, 0, stream>>>(kc);
        kfft_rows_fwd<<<dim3(8, 1), TPB, 0, stream>>>(kc);

        for (int c = 0; c < nc; ++c) {
            int vbase = c * nTc;
            if (vbase >= B) break;
            int n = B - vbase < nTc ? B - vbase : nTc;
            k_gather<<<dim3(n), TPB, 0, stream>>>(Gm, idx, A, hnh, bchirp, P, NB, NL, vbase);
            kfft_cols_fwd<<<dim3(8, n), TPB, 0, stream>>>(P);
            kfft_rows_fwd<<<dim3(8, n), TPB, 0, stream>>>(P);
            kfft_rows_inv<<<dim3(8, n), TPB, 0, stream>>>(P, kc);
            kfft_cols_inv<<<dim3(8, n), TPB, 0, stream>>>(P);
            k_fin<<<dim3(32, n), TPB, 0, stream>>>(P, bchirp, out, NL, vbase);
        }
    } else {
        k3_idft<<<dim3(NB, ROWS), TPB, (size_t)NL * sizeof(float2), stream>>>(
            Gm, idx, A, hnh, out, NB, NL);
    }
}

// Round 2
// 1504.462 us; speedup vs baseline: 2.3005x; 1.2055x over previous
//
#include <hip/hip_runtime.h>

#define TPB 256
#define TPF 1024
constexpr int LS = 264600;          // 6.0 s * 44100 Hz
constexpr int N1 = 525;             // LS = N1 * N2
constexpr int N2 = 504;
constexpr int ROWS = 32;            // S*C = 16*2
constexpr int M_FFT = 16384;        // Bluestein conv length >= 2*NL-1 (NL<=8192)
constexpr float TWO_PI_F = 6.28318530717958647692f;
constexpr float PI_F     = 3.14159265358979323846f;

__device__ __forceinline__ int rev7(int x) { return (int)(__brev((unsigned)x) >> 25); }
__device__ __forceinline__ float2 cmul(float2 a, float2 b) {
    return make_float2(a.x * b.x - a.y * b.y, a.x * b.y + a.y * b.x);
}
// XOR-swizzled LDS index for the fused 128x128 array: uniform bank-pair
// distribution for row-wise, column-wise and linear access (no padding, 128 KiB).
__device__ __forceinline__ int sidx(int hi, int lo) {
    return (hi << 7) + (lo ^ (hi & 15));
}

// ---------------------------------------------------------------------------
// K0: per-bin scan of G for nonzero head/tail block sizes (exact-0 padding).
// ---------------------------------------------------------------------------
__global__ void k0_scan(const float* __restrict__ G, int NL, int* __restrict__ hnh) {
    const int j = blockIdx.x;
    __shared__ int s_first, s_last;
    if (threadIdx.x == 0) { s_first = NL; s_last = -1; }
    __syncthreads();
    const float* Gj = G + (size_t)j * NL;
    for (int m = threadIdx.x; m < NL; m += blockDim.x) {
        if (Gj[m] == 0.0f) {
            atomicMin(&s_first, m);
            atomicMax(&s_last, m);
        }
    }
    __syncthreads();
    if (threadIdx.x == 0) {
        int h  = s_first;
        int nh = (s_last >= 0) ? (NL - 1 - s_last) : 0;
        hnh[2 * j]     = h;
        hnh[2 * j + 1] = nh;
    }
}

// ---------------------------------------------------------------------------
// K1: 525-point DFT per (n2, r), split 525 = 25 x 21 (Cooley-Tukey in LDS).
// ---------------------------------------------------------------------------
__global__ __launch_bounds__(TPB) void k1_dft525(const float* __restrict__ x,
                                                 float2* __restrict__ A) {
    const int n2 = blockIdx.x;
    const int r  = blockIdx.y;
    __shared__ float  xs[N1];
    __shared__ float2 ys[N1];
    __shared__ float2 w25[25];
    __shared__ float2 w21[21];
    const float* xr = x + (size_t)r * LS + n2;
    for (int t = threadIdx.x; t < N1; t += TPB) {
        xs[t] = xr[(size_t)t * N2];
    }
    if (threadIdx.x < 25) {
        float a = -TWO_PI_F * (float)threadIdx.x / 25.0f;
        float s, c; sincosf(a, &s, &c);
        w25[threadIdx.x] = make_float2(c, s);
    } else if (threadIdx.x >= 32 && threadIdx.x < 53) {
        int k = threadIdx.x - 32;
        float a = -TWO_PI_F * (float)k / 21.0f;
        float s, c; sincosf(a, &s, &c);
        w21[k] = make_float2(c, s);
    }
    __syncthreads();
    for (int i = threadIdx.x; i < N1; i += TPB) {
        int alpha = i % 25, b = i / 25;
        float re = 0.f, im = 0.f;
        int iw = 0, it = b;
        #pragma unroll
        for (int a = 0; a < 25; ++a) {
            float  v = xs[it];
            float2 w = w25[iw];
            re = fmaf(v, w.x, re);
            im = fmaf(v, w.y, im);
            it += 21;
            iw += alpha; if (iw >= 25) iw -= 25;
        }
        float ang = -TWO_PI_F * (float)(b * alpha) / (float)N1;
        float s, c; sincosf(ang, &s, &c);
        ys[i] = make_float2(re * c - im * s, re * s + im * c);
    }
    __syncthreads();
    for (int k = threadIdx.x; k < N1; k += TPB) {
        int alpha = k % 25, beta = k / 25;
        float re = 0.f, im = 0.f;
        int iw = 0, iy = alpha;
        #pragma unroll
        for (int b = 0; b < 21; ++b) {
            float2 v = ys[iy];
            float2 w = w21[iw];
            re = fmaf(v.x, w.x, re); re = fmaf(-v.y, w.y, re);
            im = fmaf(v.x, w.y, im); im = fmaf( v.y, w.x, im);
            iy += 25;
            iw += beta; if (iw >= 21) iw -= 21;
        }
        float ang = -TWO_PI_F * (float)(k * n2) / (float)LS;
        float s, c; sincosf(ang, &s, &c);
        A[((size_t)r * N1 + k) * N2 + n2] = make_float2(re * c - im * s, re * s + im * c);
    }
}

// ---------------------------------------------------------------------------
// K2: 504-point DFT per (k1, r), split 504 = 21 x 24 (Cooley-Tukey in LDS).
// ---------------------------------------------------------------------------
__global__ __launch_bounds__(TPB) void k2_dft504(float2* __restrict__ A) {
    const int k1 = blockIdx.x;
    const int r  = blockIdx.y;
    __shared__ float2 as[N2];
    __shared__ float2 ys[N2];
    __shared__ float2 w21[21];
    __shared__ float2 w24[24];
    float2* row = A + ((size_t)r * N1 + k1) * N2;
    for (int t = threadIdx.x; t < N2; t += TPB) as[t] = row[t];
    if (threadIdx.x < 21) {
        float a = -TWO_PI_F * (float)threadIdx.x / 21.0f;
        float s, c; sincosf(a, &s, &c);
        w21[threadIdx.x] = make_float2(c, s);
    } else if (threadIdx.x >= 32 && threadIdx.x < 56) {
        int k = threadIdx.x - 32;
        float a = -TWO_PI_F * (float)k / 24.0f;
        float s, c; sincosf(a, &s, &c);
        w24[k] = make_float2(c, s);
    }
    __syncthreads();
    for (int i = threadIdx.x; i < N2; i += TPB) {
        int alpha = i % 21, b = i / 21;
        float re = 0.f, im = 0.f;
        int iw = 0, it = b;
        #pragma unroll
        for (int a = 0; a < 21; ++a) {
            float2 v = as[it];
            float2 w = w21[iw];
            re = fmaf(v.x, w.x, re); re = fmaf(-v.y, w.y, re);
            im = fmaf(v.x, w.y, im); im = fmaf( v.y, w.x, im);
            it += 24;
            iw += alpha; if (iw >= 21) iw -= 21;
        }
        float ang = -TWO_PI_F * (float)(b * alpha) / (float)N2;
        float s, c; sincosf(ang, &s, &c);
        ys[i] = make_float2(re * c - im * s, re * s + im * c);
    }
    __syncthreads();
    for (int k = threadIdx.x; k < N2; k += TPB) {
        int alpha = k % 21, beta = k / 21;
        float re = 0.f, im = 0.f;
        int iw = 0, iy = alpha;
        #pragma unroll
        for (int b = 0; b < 24; ++b) {
            float2 v = ys[iy];
            float2 w = w24[iw];
            re = fmaf(v.x, w.x, re); re = fmaf(-v.y, w.y, re);
            im = fmaf(v.x, w.y, im); im = fmaf( v.y, w.x, im);
            iy += 21;
            iw += beta; if (iw >= 24) iw -= 24;
        }
        row[k] = make_float2(re, im);
    }
}

// ---------------------------------------------------------------------------
// K_SETUP: chirp tables + 64-entry FFT-128 twiddle table (global, L1-broadcast).
// ---------------------------------------------------------------------------
__global__ void k_setup(float2* __restrict__ kc, float2* __restrict__ bchirp,
                        float2* __restrict__ twg, int NL) {
    int t = blockIdx.x * blockDim.x + threadIdx.x;
    long long twoNL = 2LL * NL;
    if (t < M_FFT) {
        long long d = 0; bool act = false;
        if (t < NL)              { d = t;        act = true; }
        else if (t > M_FFT - NL) { d = t - M_FFT; act = true; }
        float2 v = make_float2(0.f, 0.f);
        if (act) {
            long long ph = (d * d) % twoNL;
            float th = -PI_F * (float)ph / (float)NL;
            float s, c; sincosf(th, &s, &c);
            v = make_float2(c, s);
        }
        kc[t] = v;
    } else {
        int n = t - M_FFT;
        if (n < NL) {
            long long ph = ((long long)n * n) % twoNL;
            float th = PI_F * (float)ph / (float)NL;
            float s, c; sincosf(th, &s, &c);
            bchirp[n] = make_float2(c, s);
        } else if (n < NL + 64) {
            int q = n - NL;
            float th = -TWO_PI_F * (float)q / 128.0f;
            float s, c; sincosf(th, &s, &c);
            twg[q] = make_float2(c, s);
        }
    }
}

// ---------------------------------------------------------------------------
// In-LDS radix-2 FFT-128 helpers (KF path only). 16 FFTs / 256-thread block.
// ---------------------------------------------------------------------------
__device__ void fft128_dif(float2 (*ld)[129], const float2* tw, int f, int q) {
    for (int ls = 6; ls >= 0; --ls) {
        int span = 1 << ls;
        for (int b = q; b < 64; b += 16) {
            int j = b & (span - 1);
            int g = b >> ls;
            int u = (g << (ls + 1)) + j;
            int v = u + span;
            float2 A = ld[f][u], B = ld[f][v];
            float2 s = make_float2(A.x + B.x, A.y + B.y);
            float2 d = make_float2(A.x - B.x, A.y - B.y);
            ld[f][u] = s;
            ld[f][v] = cmul(d, tw[j << (6 - ls)]);
        }
        __syncthreads();
    }
}

#define FFT_PROLOG                                                        \
    __shared__ float2 ld[16][129];                                        \
    __shared__ float2 tw[64];                                             \
    if (threadIdx.x < 64) {                                               \
        float th = -TWO_PI_F * (float)threadIdx.x / 128.0f;               \
        float s, c; sincosf(th, &s, &c);                                  \
        tw[threadIdx.x] = make_float2(c, s);                              \
    }

// Forward step 1: column FFTs (over r, stride 128) + twiddle W_M^{-c*k1}.
__global__ __launch_bounds__(TPB) void kfft_cols_fwd(float2* __restrict__ P) {
    const int cg = blockIdx.x;                    // [0,8)
    const size_t vb = (size_t)blockIdx.y * M_FFT;
    FFT_PROLOG
    const int c0 = cg * 16;
    for (int i = threadIdx.x; i < 2048; i += TPB) {
        int cl = i & 15, r = i >> 4;
        ld[cl][r] = P[vb + (c0 + cl) + 128 * r];
    }
    __syncthreads();
    fft128_dif(ld, tw, threadIdx.x >> 4, threadIdx.x & 15);
    for (int i = threadIdx.x; i < 2048; i += TPB) {
        int cl = i & 15, pos = i >> 4;
        int c = c0 + cl;
        int k1 = rev7(pos);
        float th = -TWO_PI_F * (float)(c * k1) / (float)M_FFT;
        float s, co; sincosf(th, &s, &co);
        P[vb + c + 128 * pos] = cmul(ld[cl][pos], make_float2(co, s));
    }
}

// Forward step 2: row FFTs (contiguous), no twiddle.
__global__ __launch_bounds__(TPB) void kfft_rows_fwd(float2* __restrict__ P) {
    const int rg = blockIdx.x;
    const size_t vb = (size_t)blockIdx.y * M_FFT;
    FFT_PROLOG
    const int R0 = rg * 16;
    for (int i = threadIdx.x; i < 2048; i += TPB) {
        int fl = i >> 7, c = i & 127;
        ld[fl][c] = P[vb + (size_t)(R0 + fl) * 128 + c];
    }
    __syncthreads();
    fft128_dif(ld, tw, threadIdx.x >> 4, threadIdx.x & 15);
    for (int i = threadIdx.x; i < 2048; i += TPB) {
        int fl = i >> 7, pos = i & 127;
        P[vb + (size_t)(R0 + fl) * 128 + pos] = ld[fl][pos];
    }
}

// ---------------------------------------------------------------------------
// K_FUSED: one transform per block, entirely in LDS (128 KiB dynamic).
// gather -> fwd four-step FFT-16K -> xKF -> inv four-step -> xbchirp -> out.
// Mirrors the proven global pipeline kernels phase-by-phase; flat element i
// lives at mp[sidx(i>>7, i&127)].
// ---------------------------------------------------------------------------
__global__ __launch_bounds__(TPF) void k_fused(const float* __restrict__ Gm,
        const int* __restrict__ idxp, const float2* __restrict__ A,
        const int* __restrict__ hnh, const float2* __restrict__ bchirp,
        const float2* __restrict__ KF, const float2* __restrict__ twg,
        float2* __restrict__ out, int NB, int NL) {
    extern __shared__ float2 mp[];                // [16384] swizzled
    const int tid = threadIdx.x;
    const int vg = blockIdx.x;
    const int r = vg / NB, j = vg % NB;
    const int h = hnh[2 * j], nh = hnh[2 * j + 1];
    const int tail0 = NL - nh;
    const float* Gj = Gm + (size_t)j * NL;
    const int*   ij = idxp + (size_t)j * NL;
    const float2* Ar = A + (size_t)r * LS;

    // ---- gather: a[m] = G*ft[idx] * bchirp, zero-padded to M ----
    for (int i = tid; i < M_FFT; i += TPF) {
        float2 val = make_float2(0.f, 0.f);
        if (i < h || (i >= tail0 && i < NL)) {
            int k = ij[i];
            float2 f = Ar[(size_t)(k % N1) * N2 + (k / N1)];
            float  g = Gj[i];
            val = cmul(make_float2(f.x * g, f.y * g), bchirp[i]);
        }
        mp[sidx(i >> 7, i & 127)] = val;
    }
    __syncthreads();

    // ---- forward: column FFTs (DIF over hi), natural->bitrev in place ----
    for (int ls = 6; ls >= 0; --ls) {
        const int span = 1 << ls;
        for (int w = tid; w < 8192; w += TPF) {
            const int lo = w & 127, b = w >> 7;
            const int jj = b & (span - 1), g = b >> ls;
            const int u = (g << (ls + 1)) + jj, v = u + span;
            float2 Aa = mp[sidx(u, lo)], Bb = mp[sidx(v, lo)];
            float2 s = make_float2(Aa.x + Bb.x, Aa.y + Bb.y);
            float2 d = make_float2(Aa.x - Bb.x, Aa.y - Bb.y);
            mp[sidx(u, lo)] = s;
            mp[sidx(v, lo)] = cmul(d, twg[jj << (6 - ls)]);
        }
        __syncthreads();
    }
    // inter-step twiddle W_M^{-c*rev7(pos)}
    for (int i = tid; i < M_FFT; i += TPF) {
        const int c = i & 127, pos = i >> 7;
        const int k1 = rev7(pos);
        float th = -TWO_PI_F * (float)(c * k1) / (float)M_FFT;
        float s, co; sincosf(th, &s, &co);
        const int p = sidx(pos, c);
        mp[p] = cmul(mp[p], make_float2(co, s));
    }
    __syncthreads();
    // ---- forward: row FFTs (DIF over lo) ----
    for (int ls = 6; ls >= 0; --ls) {
        const int span = 1 << ls;
        for (int w = tid; w < 8192; w += TPF) {
            const int hi = w & 127, b = w >> 7;
            const int jj = b & (span - 1), g = b >> ls;
            const int u = (g << (ls + 1)) + jj, v = u + span;
            float2 Aa = mp[sidx(hi, u)], Bb = mp[sidx(hi, v)];
            float2 s = make_float2(Aa.x + Bb.x, Aa.y + Bb.y);
            float2 d = make_float2(Aa.x - Bb.x, Aa.y - Bb.y);
            mp[sidx(hi, u)] = s;
            mp[sidx(hi, v)] = cmul(d, twg[jj << (6 - ls)]);
        }
        __syncthreads();
    }
    // ---- pointwise x KF (both sides in identical scrambled layout) ----
    for (int i = tid; i < M_FFT; i += TPF) {
        const int p = sidx(i >> 7, i & 127);
        mp[p] = cmul(mp[p], KF[i]);
    }
    __syncthreads();
    // ---- inverse: row FFTs (DIT over lo), bitrev->natural ----
    for (int ls = 0; ls <= 6; ++ls) {
        const int span = 1 << ls;
        for (int w = tid; w < 8192; w += TPF) {
            const int hi = w & 127, b = w >> 7;
            const int jj = b & (span - 1), g = b >> ls;
            const int u = (g << (ls + 1)) + jj, v = u + span;
            float2 wv = twg[jj << (6 - ls)]; wv.y = -wv.y;
            float2 Aa = mp[sidx(hi, u)];
            float2 t  = cmul(mp[sidx(hi, v)], wv);
            mp[sidx(hi, u)] = make_float2(Aa.x + t.x, Aa.y + t.y);
            mp[sidx(hi, v)] = make_float2(Aa.x - t.x, Aa.y - t.y);
        }
        __syncthreads();
    }
    // twiddle W_M^{+rev7(R)*pos}
    for (int i = tid; i < M_FFT; i += TPF) {
        const int pos = i & 127, R = i >> 7;
        const int k1 = rev7(R);
        float th = TWO_PI_F * (float)(k1 * pos) / (float)M_FFT;
        float s, co; sincosf(th, &s, &co);
        const int p = sidx(R, pos);
        mp[p] = cmul(mp[p], make_float2(co, s));
    }
    __syncthreads();
    // ---- inverse: column FFTs (DIT over hi) -> natural y[n] at flat n ----
    for (int ls = 0; ls <= 6; ++ls) {
        const int span = 1 << ls;
        for (int w = tid; w < 8192; w += TPF) {
            const int lo = w & 127, b = w >> 7;
            const int jj = b & (span - 1), g = b >> ls;
            const int u = (g << (ls + 1)) + jj, v = u + span;
            float2 wv = twg[jj << (6 - ls)]; wv.y = -wv.y;
            float2 Aa = mp[sidx(u, lo)];
            float2 t  = cmul(mp[sidx(v, lo)], wv);
            mp[sidx(u, lo)] = make_float2(Aa.x + t.x, Aa.y + t.y);
            mp[sidx(v, lo)] = make_float2(Aa.x - t.x, Aa.y - t.y);
        }
        __syncthreads();
    }
    // ---- fin: out[n] = y[n] * bchirp[n] * 100/(NL*M) ----
    const float sc = 100.0f / ((float)NL * (float)M_FFT);
    float2* outv = out + (size_t)vg * NL;
    for (int n = tid; n < NL; n += TPF) {
        float2 y = cmul(mp[sidx(n >> 7, n & 127)], bchirp[n]);
        outv[n] = make_float2(y.x * sc, y.y * sc);
    }
}

// ---------------------------------------------------------------------------
// Legacy direct zoom-IDFT — fallback if NL too large or ws too small.
// ---------------------------------------------------------------------------
__global__ __launch_bounds__(TPB) void k3_idft(const float* __restrict__ G,
                                               const int*  __restrict__ idxp,
                                               const float2* __restrict__ FT,
                                               const int*  __restrict__ hnh,
                                               float2* __restrict__ out,
                                               int NB, int NL) {
    extern __shared__ float2 cls[];
    const int j = blockIdx.x;
    const int r = blockIdx.y;
    const int h  = hnh[2 * j];
    const int nh = hnh[2 * j + 1];
    const int Lg = h + nh;
    const float* Gj = G    + (size_t)j * NL;
    const int*   ij = idxp + (size_t)j * NL;

    for (int t = threadIdx.x; t < Lg; t += TPB) {
        int m = (t < h) ? t : (NL - nh + (t - h));
        int k = ij[m];
        float2 f = FT[((size_t)r * N1 + (k % N1)) * N2 + (k / N1)];
        float  g = Gj[m];
        cls[t] = make_float2(f.x * g, f.y * g);
    }
    __syncthreads();

    const float scale = 100.0f / (float)NL;
    const float w0 = TWO_PI_F / (float)NL;
    float2* outr = out + ((size_t)r * NB + j) * NL;

    for (int n_base = 0; n_base < NL; n_base += 4 * TPB) {
        int   n[4];
        float are[4], aim[4], twr[4], twi[4], str[4], sti[4];
        #pragma unroll
        for (int u = 0; u < 4; ++u) {
            n[u] = n_base + u * TPB + (int)threadIdx.x;
            are[u] = 0.f; aim[u] = 0.f;
            float s, c; sincosf(w0 * (float)(n[u] % NL), &s, &c);
            str[u] = c; sti[u] = s;
            twr[u] = 1.f; twi[u] = 0.f;
        }
        for (int t = 0; t < h; ++t) {
            if ((t & 255) == 0) {
                #pragma unroll
                for (int u = 0; u < 4; ++u) {
                    int mm = (int)(((long long)t * (long long)n[u]) % NL);
                    float s, c; sincosf(w0 * (float)mm, &s, &c);
                    twr[u] = c; twi[u] = s;
                }
            }
            float2 cv = cls[t];
            #pragma unroll
            for (int u = 0; u < 4; ++u) {
                are[u] = fmaf(cv.x, twr[u], are[u]);
                are[u] = fmaf(-cv.y, twi[u], are[u]);
                aim[u] = fmaf(cv.x, twi[u], aim[u]);
                aim[u] = fmaf(cv.y, twr[u], aim[u]);
                float nr = twr[u] * str[u] - twi[u] * sti[u];
                float ni = twr[u] * sti[u] + twi[u] * str[u];
                twr[u] = nr; twi[u] = ni;
            }
        }
        const int m0 = NL - nh;
        for (int t = 0; t < nh; ++t) {
            if ((t & 255) == 0) {
                #pragma unroll
                for (int u = 0; u < 4; ++u) {
                    int mm = (int)(((long long)(m0 + t) * (long long)n[u]) % NL);
                    float s, c; sincosf(w0 * (float)mm, &s, &c);
                    twr[u] = c; twi[u] = s;
                }
            }
            float2 cv = cls[h + t];
            #pragma unroll
            for (int u = 0; u < 4; ++u) {
                are[u] = fmaf(cv.x, twr[u], are[u]);
                are[u] = fmaf(-cv.y, twi[u], are[u]);
                aim[u] = fmaf(cv.x, twi[u], aim[u]);
                aim[u] = fmaf(cv.y, twr[u], aim[u]);
                float nr = twr[u] * str[u] - twi[u] * sti[u];
                float ni = twr[u] * sti[u] + twi[u] * str[u];
                twr[u] = nr; twi[u] = ni;
            }
        }
        #pragma unroll
        for (int u = 0; u < 4; ++u) {
            if (n[u] < NL) outr[n[u]] = make_float2(are[u] * scale, aim[u] * scale);
        }
    }
}

// ---------------------------------------------------------------------------
static inline size_t align256(size_t x) { return (x + 255) & ~(size_t)255; }

extern "C" void kernel_launch(void* const* d_in, const int* in_sizes, int n_in,
                              void* d_out, int out_size, void* d_ws, size_t ws_size,
                              hipStream_t stream) {
    const float* x   = (const float*)d_in[0];
    const float* Gm  = (const float*)d_in[1];
    const int*   idx = (const int*)d_in[2];
    float2*      out = (float2*)d_out;

    const int p  = in_sizes[1];
    const int NB = (p % 114 == 0) ? 114 : 115;
    const int NL = p / NB;
    const int B  = NB * ROWS;

    // ws layout: hnh | bchirp | twg | kc(KF) | A
    size_t hnh_off    = 0;
    size_t bchirp_off = align256(hnh_off + 2048);
    size_t twg_off    = align256(bchirp_off + (size_t)NL * 8);
    size_t kc_off     = align256(twg_off + 64 * 8);
    size_t A_off      = align256(kc_off + (size_t)M_FFT * 8);
    size_t need       = A_off + (size_t)ROWS * LS * 8;

    int*    hnh    = (int*)((char*)d_ws + hnh_off);
    float2* bchirp = (float2*)((char*)d_ws + bchirp_off);
    float2* twg    = (float2*)((char*)d_ws + twg_off);
    float2* kc     = (float2*)((char*)d_ws + kc_off);
    float2* A      = (float2*)((char*)d_ws + A_off);

    k0_scan<<<dim3(NB), TPB, 0, stream>>>(Gm, NL, hnh);
    k1_dft525<<<dim3(N2, ROWS), TPB, 0, stream>>>(x, A);
    k2_dft504<<<dim3(N1, ROWS), TPB, 0, stream>>>(A);

    const bool fused_ok = (2 * NL - 1 <= M_FFT) && (need <= ws_size);
    if (fused_ok) {
        (void)hipFuncSetAttribute((const void*)k_fused,
                                  hipFuncAttributeMaxDynamicSharedMemorySize,
                                  M_FFT * (int)sizeof(float2));
        int setup_blocks = (M_FFT + NL + 64 + TPB - 1) / TPB;
        k_setup<<<dim3(setup_blocks), TPB, 0, stream>>>(kc, bchirp, twg, NL);
        // KF = fwd-FFT(kc) in the pipeline's stored (scrambled) layout
        kfft_cols_fwd<<<dim3(8, 1), TPB, 0, stream>>>(kc);
        kfft_rows_fwd<<<dim3(8, 1), TPB, 0, stream>>>(kc);
        k_fused<<<dim3(B), TPF, (size_t)M_FFT * sizeof(float2), stream>>>(
            Gm, idx, A, hnh, bchirp, kc, twg, out, NB, NL);
    } else {
        k3_idft<<<dim3(NB, ROWS), TPB, (size_t)NL * sizeof(float2), stream>>>(
            Gm, idx, A, hnh, out, NB, NL);
    }
}